// Round 20
// baseline (90.487 us; speedup 1.0000x reference)
//
#include <hip/hip_runtime.h>

// Problem constants: B=32, C_IN=64, C_OUT=128, K=3, H=W=128
#define BATCH 32
#define CIN   64
#define COUT  128
#define HW    128
#define OW    126            // H-K+1
#define IMG4  508032         // float4s per batch-image of out (128*126*126/4)

typedef float f4 __attribute__((ext_vector_type(4)));
typedef float f32x4 __attribute__((ext_vector_type(4)));
typedef short s8v __attribute__((ext_vector_type(8)));   // bf16x8 MFMA fragment
typedef unsigned short u16;

__device__ inline u16 bf16_rne(float v) {                // round-to-nearest-even
    unsigned b = __float_as_uint(v);
    unsigned r = b + 0x7FFF + ((b >> 16) & 1);
    return (u16)(r >> 16);
}
__device__ inline float bf16_f(u16 h) { return __uint_as_float(((unsigned)h) << 16); }

// ---- Kernel 1 (FROZEN, probed at read-roofline 21.3 us): batch-sum + pack ----
__global__ __launch_bounds__(256) void k_bsum(const float* __restrict__ x,
                                              const float* __restrict__ w,
                                              u16* __restrict__ xh,
                                              u16* __restrict__ xl,
                                              u16* __restrict__ wh,
                                              u16* __restrict__ wl) {
    __shared__ unsigned lds[128 * 17];            // packed (hi | lo<<16), pitch 17

    const int t     = threadIdx.x;
    const int hw0   = blockIdx.x * 128;
    const int cb    = blockIdx.y;                 // 0..3 -> ic0 = cb*16
    const int f4i   = t & 31;                     // f4 index over the 128-hw tile
    const int chalf = t >> 5;                     // 0..7

    const f4* __restrict__ x4 = (const f4*)x;
    const int rb = cb * 16 + chalf;               // first of 2 c-rows (other +8)
    const int hb = (hw0 >> 2) + f4i;              // f4 offset within a c-row

    f4 acc0 = {0.f, 0.f, 0.f, 0.f};
    f4 acc1 = {0.f, 0.f, 0.f, 0.f};
    #pragma unroll 4
    for (int b = 0; b < BATCH; ++b) {
        const size_t base = (size_t)b * 262144;
        acc0 += __builtin_nontemporal_load(&x4[base + (rb    ) * 4096 + hb]);
        acc1 += __builtin_nontemporal_load(&x4[base + (rb + 8) * 4096 + hb]);
    }

    #pragma unroll
    for (int j = 0; j < 4; ++j) {
        {
            const float v = acc0[j];
            const u16 h = bf16_rne(v);
            const u16 lo = bf16_rne(v - bf16_f(h));
            lds[(f4i * 4 + j) * 17 + chalf] = (unsigned)h | ((unsigned)lo << 16);
        }
        {
            const float v = acc1[j];
            const u16 h = bf16_rne(v);
            const u16 lo = bf16_rne(v - bf16_f(h));
            lds[(f4i * 4 + j) * 17 + chalf + 8] = (unsigned)h | ((unsigned)lo << 16);
        }
    }
    __syncthreads();

    unsigned* __restrict__ xhu = (unsigned*)xh;
    unsigned* __restrict__ xlu = (unsigned*)xl;
    const int base = cb * 131072 + hw0 * 8;       // u32 index: tile 16384*16/2 per cb
    #pragma unroll
    for (int k = 0; k < 4; ++k) {
        const int l  = t * 4 + k;                 // 0..1023
        const int hw = l >> 3;
        const int wi = l & 7;
        const unsigned e0 = lds[hw * 17 + 2 * wi];
        const unsigned e1 = lds[hw * 17 + 2 * wi + 1];
        xhu[base + l] = (e0 & 0xFFFFu) | (e1 << 16);
        xlu[base + l] = (e0 >> 16) | (e1 & 0xFFFF0000u);
    }

    // Weight repack+split: idx = (t*128+oc)*64+ic <- w[(oc*64+ic)*9 + t]
    const int bid = blockIdx.y * 128 + blockIdx.x;
    if (bid < 288) {
        const int idx = bid * 256 + t;            // 0..73727
        const int ic = idx & 63;
        const int oc = (idx >> 6) & 127;
        const int tp = idx >> 13;
        const float v = w[(oc * 64 + ic) * 9 + tp];
        const u16 h = bf16_rne(v);
        wh[idx] = h;
        wl[idx] = bf16_rne(v - bf16_f(h));
    }
}

// ---- Kernel 2 (lever: 16-px wave tiles, 2x occupancy): bf16 MFMA conv ----
// Wave tile 32 oc x 16 px; grid (126 rows, 8 col-strips) = 1008 blocks
// -> 4032 waves = 4 waves/SIMD (was 2). 2-term hi/lo kept.
__global__ __launch_bounds__(256, 4) void k_conv(const u16* __restrict__ xh,
                                                 const u16* __restrict__ xl,
                                                 const u16* __restrict__ wh,
                                                 const float* __restrict__ bias,
                                                 float* __restrict__ out) {
    const int tid  = threadIdx.x;
    const int l    = tid & 63;
    const int ocb  = (tid >> 6) * 32;       // wave -> 32 output channels
    const int row  = blockIdx.x;            // 0..125
    const int col0 = blockIdx.y * 16;       // 0,16,...,112
    const int n = l & 15;
    const int g = l >> 4;

    f32x4 acc[2] = {};                      // [om]

    #pragma unroll
    for (int kb = 0; kb < 2; ++kb) {
        const int icoff = kb * 32 + g * 8;
        const size_t tb = (size_t)(kb * 2 + (g >> 1)) * 262144;  // tile base (u16)
        const int off = (g & 1) * 8;
        #pragma unroll
        for (int t = 0; t < 9; ++t) {
            const int ky = t / 3, kx = t % 3;
            const int r  = row + ky;                         // <= 127, in-bounds
            const int c0 = min(col0 + kx + n, 127);          // clamp: junk masked on store
            const s8v bh0 = *(const s8v*)(xh + tb + (r * 128 + c0) * 16 + off);
            const s8v bl0 = *(const s8v*)(xl + tb + (r * 128 + c0) * 16 + off);
            const int wb0 = (t * 128 + ocb + n) * 64 + icoff;
            const s8v ah0 = *(const s8v*)(wh + wb0);
            const s8v ah1 = *(const s8v*)(wh + wb0 + 16 * 64);
            acc[0] = __builtin_amdgcn_mfma_f32_16x16x32_bf16(ah0, bh0, acc[0], 0, 0, 0);
            acc[0] = __builtin_amdgcn_mfma_f32_16x16x32_bf16(ah0, bl0, acc[0], 0, 0, 0);
            acc[1] = __builtin_amdgcn_mfma_f32_16x16x32_bf16(ah1, bh0, acc[1], 0, 0, 0);
            acc[1] = __builtin_amdgcn_mfma_f32_16x16x32_bf16(ah1, bl0, acc[1], 0, 0, 0);
        }
    }

    const int col = col0 + n;
    if (col < OW) {
        #pragma unroll
        for (int om = 0; om < 2; ++om) {
            #pragma unroll
            for (int j = 0; j < 4; ++j) {
                const int oc = ocb + om * 16 + g * 4 + j;
                out[((size_t)oc * OW + row) * OW + col] = acc[om][j] + bias[oc];
            }
        }
    }
}

// ---- Kernel 3 (FROZEN, probed at write-roofline 38 us): fan-out broadcast ----
__global__ __launch_bounds__(256) void k_bcast(float* __restrict__ out) {
    f4* __restrict__ o4 = (f4*)out;
    const int r0 = blockIdx.x * 512 + threadIdx.x;
    const int r1 = r0 + 256;
    const bool ok0 = r0 < IMG4;
    const bool ok1 = r1 < IMG4;
    f4 v0 = {}; f4 v1 = {};
    if (ok0) v0 = o4[r0];
    if (ok1) v1 = o4[r1];
    #pragma unroll
    for (int b = 1; b < BATCH; ++b) {
        const size_t base = (size_t)b * IMG4;
        if (ok0) o4[base + r0] = v0;
        if (ok1) o4[base + r1] = v1;
    }
}

extern "C" void kernel_launch(void* const* d_in, const int* in_sizes, int n_in,
                              void* d_out, int out_size, void* d_ws, size_t ws_size,
                              hipStream_t stream) {
    const float* x    = (const float*)d_in[0];   // [32,64,128,128]
    const float* w    = (const float*)d_in[1];   // [128,64,3,3]
    const float* bias = (const float*)d_in[2];   // [128,1,1]
    float* out = (float*)d_out;                  // [32,128,126,126]

    u16* xh = (u16*)d_ws;                        // 1,048,576 elems (2 MB)
    u16* xl = xh + 1048576;                      // 2 MB
    u16* wh = xl + 1048576;                      // 73,728 elems (144 KB)
    u16* wl = wh + 73728;                        // 144 KB (written, unused by conv)

    k_bsum<<<dim3(128, 4), dim3(256), 0, stream>>>(x, w, xh, xl, wh, wl);
    k_conv<<<dim3(OW, 8), dim3(256), 0, stream>>>(xh, xl, wh, bias, out);
    k_bcast<<<dim3((IMG4 + 511) / 512), dim3(256), 0, stream>>>(out);
}

// Round 21
// 81.549 us; speedup vs baseline: 1.1096x; 1.1096x over previous
//
#include <hip/hip_runtime.h>

// Problem constants: B=32, C_IN=64, C_OUT=128, K=3, H=W=128
#define BATCH 32
#define CIN   64
#define COUT  128
#define HW    128
#define OW    126            // H-K+1
#define IMG4  508032         // float4s per batch-image of out (128*126*126/4)

typedef float f4 __attribute__((ext_vector_type(4)));
typedef float f32x4 __attribute__((ext_vector_type(4)));
typedef short s8v __attribute__((ext_vector_type(8)));   // bf16x8 MFMA fragment
typedef unsigned short u16;

__device__ inline u16 bf16_rne(float v) {                // round-to-nearest-even
    unsigned b = __float_as_uint(v);
    unsigned r = b + 0x7FFF + ((b >> 16) & 1);
    return (u16)(r >> 16);
}
__device__ inline float bf16_f(u16 h) { return __uint_as_float(((unsigned)h) << 16); }

// ---- Kernel 1 (FROZEN, probed at read-roofline 21.3 us): batch-sum + pack ----
__global__ __launch_bounds__(256) void k_bsum(const float* __restrict__ x,
                                              const float* __restrict__ w,
                                              u16* __restrict__ xh,
                                              u16* __restrict__ xl,
                                              u16* __restrict__ wh,
                                              u16* __restrict__ wl) {
    __shared__ unsigned lds[128 * 17];            // packed (hi | lo<<16), pitch 17

    const int t     = threadIdx.x;
    const int hw0   = blockIdx.x * 128;
    const int cb    = blockIdx.y;                 // 0..3 -> ic0 = cb*16
    const int f4i   = t & 31;                     // f4 index over the 128-hw tile
    const int chalf = t >> 5;                     // 0..7

    const f4* __restrict__ x4 = (const f4*)x;
    const int rb = cb * 16 + chalf;               // first of 2 c-rows (other +8)
    const int hb = (hw0 >> 2) + f4i;              // f4 offset within a c-row

    f4 acc0 = {0.f, 0.f, 0.f, 0.f};
    f4 acc1 = {0.f, 0.f, 0.f, 0.f};
    #pragma unroll 4
    for (int b = 0; b < BATCH; ++b) {
        const size_t base = (size_t)b * 262144;
        acc0 += __builtin_nontemporal_load(&x4[base + (rb    ) * 4096 + hb]);
        acc1 += __builtin_nontemporal_load(&x4[base + (rb + 8) * 4096 + hb]);
    }

    #pragma unroll
    for (int j = 0; j < 4; ++j) {
        {
            const float v = acc0[j];
            const u16 h = bf16_rne(v);
            const u16 lo = bf16_rne(v - bf16_f(h));
            lds[(f4i * 4 + j) * 17 + chalf] = (unsigned)h | ((unsigned)lo << 16);
        }
        {
            const float v = acc1[j];
            const u16 h = bf16_rne(v);
            const u16 lo = bf16_rne(v - bf16_f(h));
            lds[(f4i * 4 + j) * 17 + chalf + 8] = (unsigned)h | ((unsigned)lo << 16);
        }
    }
    __syncthreads();

    unsigned* __restrict__ xhu = (unsigned*)xh;
    unsigned* __restrict__ xlu = (unsigned*)xl;
    const int base = cb * 131072 + hw0 * 8;       // u32 index: tile 16384*16/2 per cb
    #pragma unroll
    for (int k = 0; k < 4; ++k) {
        const int l  = t * 4 + k;                 // 0..1023
        const int hw = l >> 3;
        const int wi = l & 7;
        const unsigned e0 = lds[hw * 17 + 2 * wi];
        const unsigned e1 = lds[hw * 17 + 2 * wi + 1];
        xhu[base + l] = (e0 & 0xFFFFu) | (e1 << 16);
        xlu[base + l] = (e0 >> 16) | (e1 & 0xFFFF0000u);
    }

    // Weight repack+split: idx = (t*128+oc)*64+ic <- w[(oc*64+ic)*9 + t]
    const int bid = blockIdx.y * 128 + blockIdx.x;
    if (bid < 288) {
        const int idx = bid * 256 + t;            // 0..73727
        const int ic = idx & 63;
        const int oc = (idx >> 6) & 127;
        const int tp = idx >> 13;
        const float v = w[(oc * 64 + ic) * 9 + tp];
        const u16 h = bf16_rne(v);
        wh[idx] = h;
        wl[idx] = bf16_rne(v - bf16_f(h));
    }
}

// ---- Kernel 2 (lever: SINGLE-TERM bf16): conv via MFMA -> out batch 0 ----
// R19 geometry (32-px wave tiles, grid (126,4) — best) with x_lo term dropped:
// D = w_hi * x_hi only. Per (kb,t) group: 4 loads (was 6), 4 MFMAs (was 8).
// Error budget: dropped terms random-walk sigma~0.3, absmax expected ~6 < 13.12.
__global__ __launch_bounds__(256) void k_conv(const u16* __restrict__ xh,
                                              const u16* __restrict__ wh,
                                              const float* __restrict__ bias,
                                              float* __restrict__ out) {
    const int tid  = threadIdx.x;
    const int l    = tid & 63;
    const int ocb  = (tid >> 6) * 32;       // wave -> 32 output channels
    const int row  = blockIdx.x;            // 0..125
    const int col0 = blockIdx.y * 32;       // 0,32,64,96
    const int n = l & 15;
    const int g = l >> 4;

    f32x4 acc[2][2] = {};                   // [om][on]

    #pragma unroll
    for (int kb = 0; kb < 2; ++kb) {
        const int icoff = kb * 32 + g * 8;
        const size_t tb = (size_t)(kb * 2 + (g >> 1)) * 262144;  // tile base (u16)
        const int off = (g & 1) * 8;
        #pragma unroll
        for (int t = 0; t < 9; ++t) {
            const int ky = t / 3, kx = t % 3;
            const int r  = row + ky;                         // <= 127, in-bounds
            const int c0 = min(col0 + kx + n, 127);          // clamp: junk masked on store
            const int c1 = min(col0 + kx + 16 + n, 127);
            const s8v bh0 = *(const s8v*)(xh + tb + (r * 128 + c0) * 16 + off);
            const s8v bh1 = *(const s8v*)(xh + tb + (r * 128 + c1) * 16 + off);
            const int wb0 = (t * 128 + ocb + n) * 64 + icoff;
            const s8v ah0 = *(const s8v*)(wh + wb0);
            const s8v ah1 = *(const s8v*)(wh + wb0 + 16 * 64);
            acc[0][0] = __builtin_amdgcn_mfma_f32_16x16x32_bf16(ah0, bh0, acc[0][0], 0, 0, 0);
            acc[0][1] = __builtin_amdgcn_mfma_f32_16x16x32_bf16(ah0, bh1, acc[0][1], 0, 0, 0);
            acc[1][0] = __builtin_amdgcn_mfma_f32_16x16x32_bf16(ah1, bh0, acc[1][0], 0, 0, 0);
            acc[1][1] = __builtin_amdgcn_mfma_f32_16x16x32_bf16(ah1, bh1, acc[1][1], 0, 0, 0);
        }
    }

    #pragma unroll
    for (int om = 0; om < 2; ++om) {
        #pragma unroll
        for (int j = 0; j < 4; ++j) {
            const int oc = ocb + om * 16 + g * 4 + j;
            const float bv = bias[oc];
            #pragma unroll
            for (int on = 0; on < 2; ++on) {
                const int col = col0 + on * 16 + n;
                if (col < OW)
                    out[((size_t)oc * OW + row) * OW + col] = acc[om][on][j] + bv;
            }
        }
    }
}

// ---- Kernel 3 (FROZEN, probed at write-roofline 38 us): fan-out broadcast ----
__global__ __launch_bounds__(256) void k_bcast(float* __restrict__ out) {
    f4* __restrict__ o4 = (f4*)out;
    const int r0 = blockIdx.x * 512 + threadIdx.x;
    const int r1 = r0 + 256;
    const bool ok0 = r0 < IMG4;
    const bool ok1 = r1 < IMG4;
    f4 v0 = {}; f4 v1 = {};
    if (ok0) v0 = o4[r0];
    if (ok1) v1 = o4[r1];
    #pragma unroll
    for (int b = 1; b < BATCH; ++b) {
        const size_t base = (size_t)b * IMG4;
        if (ok0) o4[base + r0] = v0;
        if (ok1) o4[base + r1] = v1;
    }
}

extern "C" void kernel_launch(void* const* d_in, const int* in_sizes, int n_in,
                              void* d_out, int out_size, void* d_ws, size_t ws_size,
                              hipStream_t stream) {
    const float* x    = (const float*)d_in[0];   // [32,64,128,128]
    const float* w    = (const float*)d_in[1];   // [128,64,3,3]
    const float* bias = (const float*)d_in[2];   // [128,1,1]
    float* out = (float*)d_out;                  // [32,128,126,126]

    u16* xh = (u16*)d_ws;                        // 1,048,576 elems (2 MB)
    u16* xl = xh + 1048576;                      // 2 MB (written, unused by conv)
    u16* wh = xl + 1048576;                      // 73,728 elems (144 KB)
    u16* wl = wh + 73728;                        // 144 KB (written, unused by conv)

    k_bsum<<<dim3(128, 4), dim3(256), 0, stream>>>(x, w, xh, xl, wh, wl);
    k_conv<<<dim3(OW, 4), dim3(256), 0, stream>>>(xh, wh, bias, out);
    k_bcast<<<dim3((IMG4 + 511) / 512), dim3(256), 0, stream>>>(out);
}